// Round 11
// baseline (234.030 us; speedup 1.0000x reference)
//
#include <hip/hip_runtime.h>
#include <math.h>

constexpr int EMBED = 1024;
constexpr int HEADS = 16;
constexpr int HDIM  = 64;
constexpr int BATCH = 2;
constexpr int SEQ   = 2048;
constexpr int MTOT  = BATCH * SEQ;   // 4096
constexpr int KSPL  = 3 * EMBED;     // 3072: K' for the 3-term split GEMM
constexpr int LDK   = 2 * EMBED;     // 2048: physical [hi|lo] row width
constexpr int BHSZ  = SEQ * HDIM;    // 131072 elems per (b,h) slice

typedef unsigned short u16;
using bf16x8 = __attribute__((ext_vector_type(8))) short;
using f32x4  = __attribute__((ext_vector_type(4))) float;
using f32x16 = __attribute__((ext_vector_type(16))) float;
using u32x4  = __attribute__((ext_vector_type(4))) unsigned int;

__device__ __forceinline__ u16 f2bf(float f) {
    unsigned u = __builtin_bit_cast(unsigned, f);
    return (u16)((u + 0x7fffu + ((u >> 16) & 1u)) >> 16);
}
__device__ __forceinline__ float bf2f(u16 h) {
    unsigned u = ((unsigned)h) << 16;
    return __builtin_bit_cast(float, u);
}
__device__ __forceinline__ unsigned cvtpk(float lo, float hi) {
    unsigned r;
    asm("v_cvt_pk_bf16_f32 %0, %1, %2" : "=v"(r) : "v"(lo), "v"(hi));
    return r;
}

#define GLOAD16(gp, lp) __builtin_amdgcn_global_load_lds( \
    (const __attribute__((address_space(1))) unsigned int*)(gp), \
    (__attribute__((address_space(3))) unsigned int*)(lp), 16, 0, 0)

// ---------------------------------------------------------------------------
// Split f32 rows into bf16 [hi|lo]; w_qkv rows permuted to [which][h][d].
// ---------------------------------------------------------------------------
__global__ __launch_bounds__(256)
void convert_split(const float* __restrict__ X, const float* __restrict__ Wq,
                   const float* __restrict__ Wp,
                   u16* __restrict__ Xs, u16* __restrict__ Wqs, u16* __restrict__ Wps)
{
    int m = blockIdx.x;                 // 0..8191
    int k = threadIdx.x * 4;
    const float* src; u16* dst;
    if (m < 4096) {
        src = X + (size_t)m * EMBED;          dst = Xs + (size_t)m * LDK;
    } else if (m < 7168) {
        int f = m - 4096;
        int h = f / 192, rem = f - h * 192, d = rem / 3, wq = rem - d * 3;
        int nrow = wq * 1024 + h * 64 + d;
        src = Wq + (size_t)f * EMBED;         dst = Wqs + (size_t)nrow * LDK;
    } else {
        int lm = m - 7168;
        src = Wp + (size_t)lm * EMBED;        dst = Wps + (size_t)lm * LDK;
    }
    float4 v = *(const float4*)(src + k);
    ushort4 hi, lo;
    hi.x = f2bf(v.x); lo.x = f2bf(v.x - bf2f(hi.x));
    hi.y = f2bf(v.y); lo.y = f2bf(v.y - bf2f(hi.y));
    hi.z = f2bf(v.z); lo.z = f2bf(v.z - bf2f(hi.z));
    hi.w = f2bf(v.w); lo.w = f2bf(v.w - bf2f(hi.w));
    *(ushort4*)(dst + k)         = hi;
    *(ushort4*)(dst + EMBED + k) = lo;
}

// ===========================================================================
// QKV GEMM, 256x256 tile, 8 waves, BK=32, FOUR LDS buffers (128 KB),
// depth-3 counted-vmcnt pipeline (T3+T4):
//   iter kt: ds_read buf[kt&3]; issue stage(kt+3)->buf[(kt+3)&3];
//            32 MFMA (setprio); lgkmcnt(0); vmcnt(8); s_barrier.
// vmcnt(8) keeps stages kt+2,kt+3 (8 loads/wave) in flight ACROSS the
// barrier and only forces stage(kt+1) retired -- no drain-to-0 (m218).
// Write hazard: stage(kt+3) overwrites buf read at kt-1, whose ds_reads
// retired at the kt-1 barrier (lgkmcnt(0) before barrier).
// Swizzle pair (R8-verified, conflict-free): source chunk c^((row>>1)&3),
// read chunk (lane>>4)^((lane>>1)&3).
// ===========================================================================
__device__ __forceinline__ void stage4(
    const u16* __restrict__ A, const u16* __restrict__ B,
    u16* SHu, int buf, int kt, int tid)
{
    const int k0 = kt * 32;
    const int ka = k0 < 2048 ? k0 : k0 - 2048;   // A segs [hi|lo|hi]
    const int kb = k0 < 1024 ? k0 : k0 - 1024;   // B segs [hi|hi|lo]
    u16* dst = SHu + buf * 16384;
    #pragma unroll
    for (int i = 0; i < 2; ++i) {
        const int s    = i * 512 + tid;          // slot 0..1023
        const int row  = s >> 2;                 // 0..255
        const int gcol = ((s & 3) ^ ((row >> 1) & 3)) * 8;
        GLOAD16(A + (size_t)row * LDK + ka + gcol, dst + s * 8);
        GLOAD16(B + (size_t)row * LDK + kb + gcol, dst + 8192 + s * 8);
    }
}

__global__ __launch_bounds__(512)
void gemm_qkv_pipe(const u16* __restrict__ Xs, const u16* __restrict__ Wqs,
                   u16* __restrict__ Qhi, u16* __restrict__ Qlo,
                   u16* __restrict__ Khi, u16* __restrict__ Klo,
                   u16* __restrict__ Vt)
{
    __shared__ __align__(16) u16 SHu[65536];   // 128 KB: 4 bufs x (A 16KB | B 16KB)
    const int bid = blockIdx.x;                // 192
    const int xcd = bid & 7, j = bid >> 3;     // j in [0,24)
    const int bm  = xcd * 2 + (j & 1);         // 0..15 (256-row tiles)
    const int bn  = j >> 1;                    // 0..11 (256-col tiles)
    const int tid = threadIdx.x, wid = tid >> 6, lane = tid & 63;
    const int wr  = wid >> 2, wc = wid & 3;    // wave: 128-row x 64-col subtile

    const u16* Ab = Xs  + (size_t)bm * 256 * LDK;
    const u16* Bb = Wqs + (size_t)bn * 256 * LDK;

    const int frow = lane & 15;
    const int kg8s = ((lane >> 4) ^ ((lane >> 1) & 3)) * 8;

    f32x4 acc[8][4] = {};

    stage4(Ab, Bb, SHu, 0, 0, tid);
    stage4(Ab, Bb, SHu, 1, 1, tid);
    stage4(Ab, Bb, SHu, 2, 2, tid);
    asm volatile("s_waitcnt vmcnt(8)" ::: "memory");   // stage(0) retired
    __builtin_amdgcn_s_barrier();

    for (int kt = 0; kt < 96; ++kt) {
        const u16* bufp = SHu + (kt & 3) * 16384;
        bf16x8 bf[4], af[8];
        #pragma unroll
        for (int ni = 0; ni < 4; ++ni)
            bf[ni] = *(const bf16x8*)&bufp[8192 + (wc * 64 + ni * 16 + frow) * 32 + kg8s];
        #pragma unroll
        for (int mi = 0; mi < 8; ++mi)
            af[mi] = *(const bf16x8*)&bufp[(wr * 128 + mi * 16 + frow) * 32 + kg8s];
        if (kt + 3 < 96) stage4(Ab, Bb, SHu, (kt + 3) & 3, kt + 3, tid);
        __builtin_amdgcn_s_setprio(1);
        #pragma unroll
        for (int mi = 0; mi < 8; ++mi)
            #pragma unroll
            for (int ni = 0; ni < 4; ++ni)
                acc[mi][ni] = __builtin_amdgcn_mfma_f32_16x16x32_bf16(
                    af[mi], bf[ni], acc[mi][ni], 0, 0, 0);
        __builtin_amdgcn_s_setprio(0);
        asm volatile("s_waitcnt lgkmcnt(0)" ::: "memory");
        if (kt <= 92) { asm volatile("s_waitcnt vmcnt(8)" ::: "memory"); }
        else          { asm volatile("s_waitcnt vmcnt(0)" ::: "memory"); }
        __builtin_amdgcn_s_barrier();
    }

    // ---- epilogue (identical to R10): per wave one (which, head) ----
    const int f_base = bn * 256 + wc * 64;
    const int which  = f_base >> 10;
    const int h      = (f_base >> 6) & 15;
    char* T = (char*)(SHu + wid * 8192);       // wave-private 16 KB

    #pragma unroll
    for (int hp = 0; hp < 2; ++hp) {
        const int ng  = bm * 256 + wr * 128 + hp * 64;
        const int b_  = ng >> 11;
        const int n0w = ng & 2047;
        const size_t bhb = (size_t)(b_ * HEADS + h) * BHSZ;

        if (which < 2) {
            u16* dstH = (which == 0 ? Qhi : Khi) + bhb;
            u16* dstL = (which == 0 ? Qlo : Klo) + bhb;
            #pragma unroll
            for (int pass = 0; pass < 2; ++pass) {
                u16* dst = pass ? dstL : dstH;
                #pragma unroll
                for (int mi = 0; mi < 4; ++mi)
                    #pragma unroll
                    for (int ni = 0; ni < 4; ++ni)
                        #pragma unroll
                        for (int r = 0; r < 4; ++r) {
                            float v = acc[hp * 4 + mi][ni][r];
                            u16 hi = f2bf(v);
                            u16 ov = pass ? f2bf(v - bf2f(hi)) : hi;
                            int nl = ((lane >> 4) << 2) + mi * 16 + r;
                            int dl = ni * 16 + (lane & 15);
                            *(u16*)(T + nl * 128 + ((dl * 2) ^ ((nl & 7) << 4))) = ov;
                        }
                #pragma unroll
                for (int t2 = 0; t2 < 2; ++t2)
                    #pragma unroll
                    for (int dt = 0; dt < 4; ++dt) {
                        int nl   = t2 * 32 + (lane & 31);
                        int doff = (dt * 16 + (lane >> 5) * 8) * 2;
                        bf16x8 fr = *(const bf16x8*)(T + nl * 128 + (doff ^ ((nl & 7) << 4)));
                        int tile = (n0w >> 5) + t2;
                        *(bf16x8*)&dst[(size_t)(tile * 4 + dt) * 512 + lane * 8] = fr;
                    }
            }
        } else {
            #pragma unroll
            for (int mi = 0; mi < 4; ++mi)
                #pragma unroll
                for (int ni = 0; ni < 4; ++ni)
                    #pragma unroll
                    for (int r = 0; r < 4; ++r) {
                        int nl = ((lane >> 4) << 2) + mi * 16 + r;
                        int dl = ni * 16 + (lane & 15);
                        *(u16*)(T + nl * 128 + ((dl * 2) ^ ((nl & 7) << 4))) =
                            f2bf(acc[hp * 4 + mi][ni][r]);
                    }
            u16* dst = Vt + bhb;
            #pragma unroll
            for (int t2 = 0; t2 < 2; ++t2)
                #pragma unroll
                for (int dtv = 0; dtv < 2; ++dtv)
                    #pragma unroll
                    for (int kt2 = 0; kt2 < 2; ++kt2) {
                        int dcol = (dtv * 32 + (lane & 31)) * 2;
                        int nb   = t2 * 32 + kt2 * 16 + (lane >> 5) * 8;
                        bf16x8 fr;
                        #pragma unroll
                        for (int j2 = 0; j2 < 8; ++j2) {
                            int nl = nb + j2;
                            fr[j2] = *(const short*)(T + nl * 128 + (dcol ^ ((nl & 7) << 4)));
                        }
                        int tile = (n0w >> 5) + t2;
                        *(bf16x8*)&dst[(size_t)(((tile * 2 + dtv) * 2 + kt2) * 64 + lane) * 8] = fr;
                    }
        }
    }
}

// ---------------------------------------------------------------------------
// Proj GEMM (unchanged R8-R10 structure: 128² depth-2 prefetch + T2 swizzle).
// ---------------------------------------------------------------------------
__device__ __forceinline__ void stage_pf(
    const u16* __restrict__ A, const u16* __restrict__ B,
    u16* As, u16* Bs, int buf, int t, int wid, int lane)
{
    const int k0 = t * 32;
    const int ka = k0 < 2048 ? k0 : k0 - 2048;
    const int kb = k0 < 1024 ? k0 : k0 - 1024;
    const int srow = lane >> 2;
    const int sc   = (((lane & 3) ^ ((lane >> 3) & 3))) * 8;
    u16* ab = As + buf * 4096;
    u16* bb = Bs + buf * 4096;
    #pragma unroll
    for (int i = 0; i < 2; ++i) {
        const int rb = wid * 32 + i * 16;
        GLOAD16(A + (size_t)(rb + srow) * LDK + ka + sc, ab + rb * 32);
        GLOAD16(B + (size_t)(rb + srow) * LDK + kb + sc, bb + rb * 32);
    }
}

__device__ __forceinline__ void mfma_loop_pf(
    const u16* __restrict__ Ab, const u16* __restrict__ Bb,
    u16* As, u16* Bs, f32x4 (&acc)[4][4], int wid, int lane)
{
    constexpr int NT = KSPL / 32;   // 96
    const int wr = wid >> 1, wc = wid & 1;
    const int frow = lane & 15;
    const int kg8s = (((lane >> 4) ^ ((lane >> 1) & 3))) * 8;

    stage_pf(Ab, Bb, As, Bs, 0, 0, wid, lane);
    stage_pf(Ab, Bb, As, Bs, 1, 1, wid, lane);
    asm volatile("s_waitcnt vmcnt(4)" ::: "memory");
    __builtin_amdgcn_s_barrier();
    __builtin_amdgcn_sched_barrier(0);

    int cb = 0, sb = 2;
    for (int t = 0; t < NT; ++t) {
        if (t + 2 < NT) stage_pf(Ab, Bb, As, Bs, sb, t + 2, wid, lane);
        const u16* ap = As + cb * 4096;
        const u16* bp = Bs + cb * 4096;
        bf16x8 a[4], b[4];
        #pragma unroll
        for (int mi = 0; mi < 4; ++mi)
            a[mi] = *(const bf16x8*)&ap[(wr * 64 + mi * 16 + frow) * 32 + kg8s];
        #pragma unroll
        for (int ni = 0; ni < 4; ++ni)
            b[ni] = *(const bf16x8*)&bp[(wc * 64 + ni * 16 + frow) * 32 + kg8s];
        #pragma unroll
        for (int mi = 0; mi < 4; ++mi)
            #pragma unroll
            for (int ni = 0; ni < 4; ++ni)
                acc[mi][ni] = __builtin_amdgcn_mfma_f32_16x16x32_bf16(
                    a[mi], b[ni], acc[mi][ni], 0, 0, 0);
        __builtin_amdgcn_sched_barrier(0);
        asm volatile("s_waitcnt lgkmcnt(0)" ::: "memory");
        if (t + 2 < NT) { asm volatile("s_waitcnt vmcnt(4)" ::: "memory"); }
        else            { asm volatile("s_waitcnt vmcnt(0)" ::: "memory"); }
        __builtin_amdgcn_s_barrier();
        __builtin_amdgcn_sched_barrier(0);
        cb = cb == 2 ? 0 : cb + 1;
        sb = sb == 2 ? 0 : sb + 1;
    }
}

__global__ __launch_bounds__(256)
void gemm_proj_mfma(const u16* __restrict__ CTXs, const u16* __restrict__ Wps,
                    const float* __restrict__ bias, float* __restrict__ Out)
{
    __shared__ __align__(16) u16 SH[6 * 4096];
    const int bid = blockIdx.x;                  // 256
    const int xcd = bid & 7, j = bid >> 3;       // j in [0,32)
    const int bm  = xcd * 4 + (j & 3);           // 0..31
    const int bn  = j >> 2;                      // 0..7
    const int wid = threadIdx.x >> 6, lane = threadIdx.x & 63;
    const int wr = wid >> 1, wc = wid & 1;

    f32x4 acc[4][4] = {};
    mfma_loop_pf(CTXs + (size_t)bm * 128 * LDK, Wps + (size_t)bn * 128 * LDK,
                 SH, SH + 3 * 4096, acc, wid, lane);

    const int m0 = bm * 128 + wr * 64 + ((lane >> 4) << 2);
    #pragma unroll
    for (int ni = 0; ni < 4; ++ni) {
        const int f  = bn * 128 + wc * 64 + ni * 16 + (lane & 15);
        const float bv = bias[f];
        #pragma unroll
        for (int mi = 0; mi < 4; ++mi) {
            const int m = m0 + mi * 16;
            #pragma unroll
            for (int r = 0; r < 4; ++r)
                Out[(size_t)(m + r) * EMBED + f] = fmaxf(acc[mi][ni][r] + bv, 0.f);
        }
    }
}

// ---------------------------------------------------------------------------
// Flash attention (unchanged from R6-R10).
// ---------------------------------------------------------------------------
__global__ __launch_bounds__(256)
void attn_mfma(const u16* __restrict__ Qhi, const u16* __restrict__ Qlo,
               const u16* __restrict__ Khi, const u16* __restrict__ Klo,
               const u16* __restrict__ Vt,  u16* __restrict__ CTXs)
{
    __shared__ __align__(16) float Lot[2][64][33];
    __shared__ float Lml[2][2][32];
    __shared__ __align__(16) float Ol[2][32][68];

    const int bid  = blockIdx.x;                     // 1024
    const int swz  = (bid & 7) * 128 + (bid >> 3);
    const int bh   = swz >> 5;
    const int qp   = swz & 31;
    const int wid  = threadIdx.x >> 6;
    const int lane = threadIdx.x & 63;
    const int col  = lane & 31;
    const int g    = lane >> 5;
    const int qt   = wid >> 1;
    const int kh   = wid & 1;

    const int q0   = qp * 64 + qt * 32;
    const int b_   = bh / HEADS;
    const int h    = bh % HEADS;
    const int tbeg = kh * (SEQ / 2 / 32);
    const int tend = tbeg + SEQ / 2 / 32;

    const size_t bhb = (size_t)bh * BHSZ;
    const u16* kb_hi = Khi + bhb + (size_t)lane * 8;
    const u16* kb_lo = Klo + bhb + (size_t)lane * 8;
    const u16* vb    = Vt  + bhb + (size_t)lane * 8;

    bf16x8 qh[4], ql[4];
    {
        const u16* qbh = Qhi + bhb + (size_t)(q0 >> 5) * 2048 + (size_t)lane * 8;
        const u16* qbl = Qlo + bhb + (size_t)(q0 >> 5) * 2048 + (size_t)lane * 8;
        #pragma unroll
        for (int dt = 0; dt < 4; ++dt) {
            qh[dt] = *(const bf16x8*)(qbh + dt * 512);
            ql[dt] = *(const bf16x8*)(qbl + dt * 512);
        }
    }

    f32x16 ot0 = {}, ot1 = {};
    float m_run = -3.0e38f, l_run = 0.0f;

    bf16x8 kfh[4], kfl[4];
    #pragma unroll
    for (int dt = 0; dt < 4; ++dt) {
        kfh[dt] = *(const bf16x8*)(kb_hi + (size_t)tbeg * 2048 + dt * 512);
        kfl[dt] = *(const bf16x8*)(kb_lo + (size_t)tbeg * 2048 + dt * 512);
    }

    for (int t = tbeg; t < tend; ++t) {
        bf16x8 vf[2][2];
        #pragma unroll
        for (int dt = 0; dt < 2; ++dt)
            #pragma unroll
            for (int kt = 0; kt < 2; ++kt)
                vf[dt][kt] = *(const bf16x8*)(vb + (size_t)t * 2048 + dt * 1024 + kt * 512);

        bf16x8 nkh[4], nkl[4];
        const bool more = (t + 1) < tend;
        if (more) {
            #pragma unroll
            for (int dt = 0; dt < 4; ++dt) {
                nkh[dt] = *(const bf16x8*)(kb_hi + (size_t)(t + 1) * 2048 + dt * 512);
                nkl[dt] = *(const bf16x8*)(kb_lo + (size_t)(t + 1) * 2048 + dt * 512);
            }
        }

        f32x16 st = {};
        #pragma unroll
        for (int dt = 0; dt < 4; ++dt) {
            st = __builtin_amdgcn_mfma_f32_32x32x16_bf16(kfh[dt], qh[dt], st, 0, 0, 0);
            st = __builtin_amdgcn_mfma_f32_32x32x16_bf16(kfh[dt], ql[dt], st, 0, 0, 0);
            st = __builtin_amdgcn_mfma_f32_32x32x16_bf16(kfl[dt], qh[dt], st, 0, 0, 0);
        }

        float mx;
        {
            float m0 = fmaxf(fmaxf(st[0], st[1]),  fmaxf(st[2], st[3]));
            float m1 = fmaxf(fmaxf(st[4], st[5]),  fmaxf(st[6], st[7]));
            float m2 = fmaxf(fmaxf(st[8], st[9]),  fmaxf(st[10], st[11]));
            float m3 = fmaxf(fmaxf(st[12], st[13]), fmaxf(st[14], st[15]));
            mx = fmaxf(fmaxf(m0, m1), fmaxf(m2, m3));
        }
        mx = fmaxf(mx, __shfl_xor(mx, 32));
        if (__ballot(mx > m_run + 8.0f)) {
            float m_new = fmaxf(m_run, mx);
            float corr  = __expf(m_run - m_new);
            l_run *= corr;
            ot0 = ot0 * corr;
            ot1 = ot1 * corr;
            m_run = m_new;
        }

        float p[16];
        #pragma unroll
        for (int r = 0; r < 16; ++r) p[r] = __expf(st[r] - m_run);
        {
            float s0 = (p[0] + p[1]) + (p[2] + p[3]);
            float s1 = (p[4] + p[5]) + (p[6] + p[7]);
            float s2 = (p[8] + p[9]) + (p[10] + p[11]);
            float s3 = (p[12] + p[13]) + (p[14] + p[15]);
            float ps = (s0 + s1) + (s2 + s3);
            ps += __shfl_xor(ps, 32);
            l_run += ps;
        }

        unsigned W0 = cvtpk(p[0],  p[1]),  W1 = cvtpk(p[2],  p[3]);
        unsigned W2 = cvtpk(p[4],  p[5]),  W3 = cvtpk(p[6],  p[7]);
        unsigned W4 = cvtpk(p[8],  p[9]),  W5 = cvtpk(p[10], p[11]);
        unsigned W6 = cvtpk(p[12], p[13]), W7 = cvtpk(p[14], p[15]);
        asm("v_permlane32_swap_b32 %0, %1" : "+v"(W0), "+v"(W2));
        asm("v_permlane32_swap_b32 %0, %1" : "+v"(W1), "+v"(W3));
        asm("v_permlane32_swap_b32 %0, %1" : "+v"(W4), "+v"(W6));
        asm("v_permlane32_swap_b32 %0, %1" : "+v"(W5), "+v"(W7));
        u32x4 t0 = {W0, W1, W2, W3};
        u32x4 t1 = {W4, W5, W6, W7};
        bf16x8 pf0 = __builtin_bit_cast(bf16x8, t0);
        bf16x8 pf1 = __builtin_bit_cast(bf16x8, t1);

        ot0 = __builtin_amdgcn_mfma_f32_32x32x16_bf16(vf[0][0], pf0, ot0, 0, 0, 0);
        ot1 = __builtin_amdgcn_mfma_f32_32x32x16_bf16(vf[1][0], pf0, ot1, 0, 0, 0);
        ot0 = __builtin_amdgcn_mfma_f32_32x32x16_bf16(vf[0][1], pf1, ot0, 0, 0, 0);
        ot1 = __builtin_amdgcn_mfma_f32_32x32x16_bf16(vf[1][1], pf1, ot1, 0, 0, 0);

        if (more) {
            #pragma unroll
            for (int dt = 0; dt < 4; ++dt) { kfh[dt] = nkh[dt]; kfl[dt] = nkl[dt]; }
        }
    }

    if (kh == 1) {
        #pragma unroll
        for (int r = 0; r < 16; ++r) {
            int d = (r & 3) + 8 * (r >> 2) + 4 * g;
            Lot[qt][d][col]      = ot0[r];
            Lot[qt][d + 32][col] = ot1[r];
        }
        if (g == 0) { Lml[qt][0][col] = m_run; Lml[qt][1][col] = l_run; }
    }
    __syncthreads();
    if (kh == 0) {
        float m1 = Lml[qt][0][col], l1 = Lml[qt][1][col];
        float m  = fmaxf(m_run, m1);
        float c0 = __expf(m_run - m), c1 = __expf(m1 - m);
        float l  = l_run * c0 + l1 * c1;
        float sc0 = c0 / (l * 32.0f);
        float sc1 = c1 / (l * 32.0f);
        #pragma unroll
        for (int r = 0; r < 16; ++r) {
            int d = (r & 3) + 8 * (r >> 2) + 4 * g;
            Ol[qt][col][d]      = ot0[r] * sc0 + Lot[qt][d][col] * sc1;
            Ol[qt][col][d + 32] = ot1[r] * sc0 + Lot[qt][d + 32][col] * sc1;
        }
        #pragma unroll
        for (int pass = 0; pass < 8; ++pass) {
            int qq = pass * 4 + (lane >> 4);
            int dd = (lane & 15) * 4;
            float4 t = *(const float4*)&Ol[qt][qq][dd];
            int m_ = b_ * SEQ + q0 + qq;
            ushort4 hv, lv;
            hv.x = f2bf(t.x); lv.x = f2bf(t.x - bf2f(hv.x));
            hv.y = f2bf(t.y); lv.y = f2bf(t.y - bf2f(hv.y));
            hv.z = f2bf(t.z); lv.z = f2bf(t.z - bf2f(hv.z));
            hv.w = f2bf(t.w); lv.w = f2bf(t.w - bf2f(hv.w));
            *(ushort4*)&CTXs[(size_t)m_ * LDK + h * HDIM + dd]         = hv;
            *(ushort4*)&CTXs[(size_t)m_ * LDK + EMBED + h * HDIM + dd] = lv;
        }
    }
}

extern "C" void kernel_launch(void* const* d_in, const int* in_sizes, int n_in,
                              void* d_out, int out_size, void* d_ws, size_t ws_size,
                              hipStream_t stream)
{
    const float* x      = (const float*)d_in[0];
    const float* w_qkv  = (const float*)d_in[1];
    const float* w_proj = (const float*)d_in[2];
    const float* b_proj = (const float*)d_in[3];
    float* out = (float*)d_out;

    const size_t seg = (size_t)BATCH * HEADS * SEQ * HDIM;   // 4 Mi elems
    char* w = (char*)d_ws;
    u16* Xs   = (u16*)w;  w += (size_t)MTOT * LDK * 2;       // 16 MiB
    u16* Wqs  = (u16*)w;  w += (size_t)3 * EMBED * LDK * 2;  // 12 MiB
    u16* Wps  = (u16*)w;  w += (size_t)EMBED * LDK * 2;      // 4 MiB
    u16* Qhi  = (u16*)w;  w += seg * 2;
    u16* Qlo  = (u16*)w;  w += seg * 2;
    u16* Khi  = (u16*)w;  w += seg * 2;
    u16* Klo  = (u16*)w;  w += seg * 2;
    u16* Vt   = (u16*)w;  w += seg * 2;
    u16* CTXs = Xs;   // Xs dead after gemm_qkv_pipe

    convert_split<<<dim3(8192), 256, 0, stream>>>(x, w_qkv, w_proj, Xs, Wqs, Wps);
    gemm_qkv_pipe<<<dim3(192), 512, 0, stream>>>(Xs, Wqs, Qhi, Qlo, Khi, Klo, Vt);
    attn_mfma<<<dim3(1024), 256, 0, stream>>>(Qhi, Qlo, Khi, Klo, Vt, CTXs);
    gemm_proj_mfma<<<dim3(256), 256, 0, stream>>>(CTXs, Wps, b_proj, out);
}